// Round 3
// baseline (378.592 us; speedup 1.0000x reference)
//
#include <hip/hip_runtime.h>

// B=8, C=64, H=256, W=512, 3x3 spherical taps, O=1, 2x2 upsample -> (8,1,512,1024) fp32.
#define Bn   8
#define Cn   64
#define Hn   256
#define Wn   512
#define HWn  (Hn * Wn)
#define TAPS 9
#define BH   4            // batches per D slot (layout: D[k*2+half][p][b4])

typedef float vfloat2 __attribute__((ext_vector_type(2)));  // NT-compatible
typedef float vfloat4 __attribute__((ext_vector_type(4)));  // NT-compatible

// ---------------------------------------------------------------------------
// Pass 1 (v2): channel-dot with float4 pixel-quad loads.
//   D[(2k+half)][p][b4] = sum_c feat[half*4+b4][c][p] * wt[c][k]
// Thread = 4 consecutive pixels x 2 batches (one quarter of B). Loads are
// vfloat4 (1 KB per wave instruction): wave-level VMEM instruction count
// drops 4x vs the dword version (1.05M -> 262K), attacking the
// VMEM-issue-rate bound that made occupancy changes a no-op.
// Double-buffered chunks of 4 channels (8 dwordx4 loads in flight/thread).
// acc 72 + buf 64 VGPRs -> __launch_bounds__(256,2); grid 512 = 2 blocks/CU.
// Weights are wave-uniform -> scalar reads. D layout identical to v1.
// ---------------------------------------------------------------------------
__global__ __launch_bounds__(256, 2) void pass1_chandot(
    const float* __restrict__ feat, const float* __restrict__ wt,
    float* __restrict__ D)
{
    const int strip = blockIdx.x & 127;              // 128 strips of 1024 px
    const int q     = blockIdx.x >> 7;               // batch quarter 0..3
    const int half  = q >> 1;
    const int pair  = q & 1;                         // batch pair within half
    const int p4    = strip * 1024 + (int)threadIdx.x * 4;
    const float* fbase = feat + ((size_t)((half * 4 + pair * 2) * Cn)) * HWn + p4;

    vfloat4 acc[TAPS][2];                            // [tap][batch-in-pair], 4 px wide
#pragma unroll
    for (int k = 0; k < TAPS; ++k)
#pragma unroll
        for (int j = 0; j < 2; ++j) acc[k][j] = (vfloat4){0.f, 0.f, 0.f, 0.f};

    vfloat4 buf[2][4][2];                            // [dbuf][chan-in-chunk][batch]

    // prologue: chunk 0 (c = 0..3)
#pragma unroll
    for (int ci = 0; ci < 4; ++ci)
#pragma unroll
        for (int j = 0; j < 2; ++j)
            buf[0][ci][j] = __builtin_nontemporal_load(
                (const vfloat4*)(fbase + (size_t)(j * Cn + ci) * HWn));

#pragma unroll
    for (int g = 0; g < 16; ++g) {
        const int cur = g & 1, nxt = cur ^ 1;
        if (g < 15) {                                // prefetch chunk g+1
            const int c0 = (g + 1) * 4;
#pragma unroll
            for (int ci = 0; ci < 4; ++ci)
#pragma unroll
                for (int j = 0; j < 2; ++j)
                    buf[nxt][ci][j] = __builtin_nontemporal_load(
                        (const vfloat4*)(fbase + (size_t)(j * Cn + c0 + ci) * HWn));
        }
#pragma unroll
        for (int ci = 0; ci < 4; ++ci) {
            const int c = g * 4 + ci;
#pragma unroll
            for (int k = 0; k < TAPS; ++k) {
                const float wv = wt[c * TAPS + k];   // uniform -> SGPR
#pragma unroll
                for (int j = 0; j < 2; ++j) {
                    acc[k][j].x = fmaf(buf[cur][ci][j].x, wv, acc[k][j].x);
                    acc[k][j].y = fmaf(buf[cur][ci][j].y, wv, acc[k][j].y);
                    acc[k][j].z = fmaf(buf[cur][ci][j].z, wv, acc[k][j].z);
                    acc[k][j].w = fmaf(buf[cur][ci][j].w, wv, acc[k][j].w);
                }
            }
        }
    }

    // store: per tap, per pixel, one float2 (= this thread's 2 batches) into
    // the 4-batch D slot. Same D layout as v1: D[(2k+half)*HWn + p]*4 + b4.
#pragma unroll
    for (int k = 0; k < TAPS; ++k) {
        float* dk = D + ((size_t)(k * 2 + half) * HWn + p4) * BH + pair * 2;
#pragma unroll
        for (int px = 0; px < 4; ++px) {
            float a0 = (px == 0) ? acc[k][0].x : (px == 1) ? acc[k][0].y
                     : (px == 2) ? acc[k][0].z : acc[k][0].w;
            float a1 = (px == 0) ? acc[k][1].x : (px == 1) ? acc[k][1].y
                     : (px == 2) ? acc[k][1].z : acc[k][1].w;
            *(float2*)(dk + (size_t)px * BH) = make_float2(a0, a1);
        }
    }
}

// ---------------------------------------------------------------------------
// Pass 2: UNCHANGED from round 1 (controlled experiment). Stage gi/gj via
// LDS, 18 coalesced float4 gathers from D, sum taps, NT-write 2x2 upsample.
// ---------------------------------------------------------------------------
__global__ __launch_bounds__(256) void pass2_gather(
    const float* __restrict__ D, const int* __restrict__ gi,
    const int* __restrict__ gj, float* __restrict__ out)
{
    __shared__ int loff[256 * TAPS];
    const int tid   = threadIdx.x;
    const int p0    = blockIdx.x * 256;
    const int gbase = p0 * TAPS;

#pragma unroll
    for (int i = tid; i < 256 * TAPS; i += 256)
        loff[i] = gi[gbase + i] * Wn + gj[gbase + i];
    __syncthreads();

    const int p = p0 + tid;
    const int w = p & (Wn - 1);
    const int h = p >> 9;

    int off[TAPS];
#pragma unroll
    for (int k = 0; k < TAPS; ++k) off[k] = loff[tid * TAPS + k];

    float4 x0[TAPS], x1[TAPS];
#pragma unroll
    for (int k = 0; k < TAPS; ++k) {
        x0[k] = *(const float4*)(D + ((size_t)(2 * k)     * HWn + off[k]) * BH);
        x1[k] = *(const float4*)(D + ((size_t)(2 * k + 1) * HWn + off[k]) * BH);
    }

    float a[Bn];
#pragma unroll
    for (int b = 0; b < Bn; ++b) a[b] = 0.f;
#pragma unroll
    for (int k = 0; k < TAPS; ++k) {
        a[0] += x0[k].x; a[1] += x0[k].y; a[2] += x0[k].z; a[3] += x0[k].w;
        a[4] += x1[k].x; a[5] += x1[k].y; a[6] += x1[k].z; a[7] += x1[k].w;
    }

#pragma unroll
    for (int b = 0; b < Bn; ++b) {
        vfloat2 vv = {a[b], a[b]};
        size_t o = ((size_t)b * (2 * Hn) + 2 * h) * (size_t)(2 * Wn) + 2 * w;
        __builtin_nontemporal_store(vv, (vfloat2*)(out + o));
        __builtin_nontemporal_store(vv, (vfloat2*)(out + o + 2 * Wn));
    }
}

// ---------------------------------------------------------------------------
// Fallback (ws too small): direct per-pixel 9x64 gather-dot.
// ---------------------------------------------------------------------------
__global__ __launch_bounds__(256) void direct_kernel(
    const float* __restrict__ feat, const float* __restrict__ wt,
    const int* __restrict__ gi, const int* __restrict__ gj,
    float* __restrict__ out)
{
    int p = blockIdx.x * blockDim.x + threadIdx.x;
    int w = p & (Wn - 1);
    int h = (p >> 9) & (Hn - 1);
    int b = p >> 17;

    int iidx = ((h << 9) | w) * TAPS;
    int off[TAPS];
#pragma unroll
    for (int k = 0; k < TAPS; ++k)
        off[k] = gi[iidx + k] * Wn + gj[iidx + k];

    float acc = 0.f;
    for (int c = 0; c < Cn; ++c) {
        const float* fc = feat + ((size_t)b * Cn + c) * HWn;
#pragma unroll
        for (int k = 0; k < TAPS; ++k)
            acc = fmaf(fc[off[k]], wt[c * TAPS + k], acc);
    }

    float2 v = make_float2(acc, acc);
    size_t o0 = ((size_t)b * (2 * Hn) + 2 * h) * (size_t)(2 * Wn) + 2 * w;
    *(float2*)(out + o0)          = v;
    *(float2*)(out + o0 + 2 * Wn) = v;
}

extern "C" void kernel_launch(void* const* d_in, const int* in_sizes, int n_in,
                              void* d_out, int out_size, void* d_ws, size_t ws_size,
                              hipStream_t stream) {
    const float* feat = (const float*)d_in[0];   // [8,64,256,512] fp32
    const float* wt   = (const float*)d_in[1];   // [1,64,3,3]     fp32
    const int*   gi   = (const int*)d_in[2];     // [256,512,9]    int32
    const int*   gj   = (const int*)d_in[3];     // [256,512,9]    int32
    float*       out  = (float*)d_out;           // [8,1,512,1024] fp32

    // D[k*2+half][p][b4]
    const size_t bytesD = (size_t)TAPS * 2 * HWn * BH * sizeof(float); // 37.75 MB

    if (ws_size >= bytesD) {
        float* D = (float*)d_ws;
        pass1_chandot<<<4 * 128, 256, 0, stream>>>(feat, wt, D);   // 512 blocks
        pass2_gather <<<HWn / 256, 256, 0, stream>>>(D, gi, gj, out);
    } else {
        direct_kernel<<<(Bn * HWn) / 256, 256, 0, stream>>>(feat, wt, gi, gj, out);
    }
}